// Round 1
// 162.425 us; speedup vs baseline: 1.0130x; 1.0130x over previous
//
#include <hip/hip_runtime.h>
#include <math.h>

#define HOURS   24
#define DPS     168          // days per sample
#define S_LEN   4032
#define NB_MAX  4096
#define NEG     -1e9f

// ========== kernel A: one sample per 1024-thread block ==========
// Lane li (0..1007) loads float4 #li of the sample: PERFECTLY coalesced
// (64 lanes x 16B contiguous = 16 cache lines / instruction, the minimum).
// 6 lanes per day (day = li/6, q = li%6, hours h = 4q..4q+3).
// Day-level argmax (jnp first-max semantics) via LDS partial scan:
// lane quads hold ascending disjoint h-ranges, within-lane scan is
// ascending-h with strict '>', so the 6-entry ascending scan with strict
// '>' reproduces argmax-first exactly.

__global__ __launch_bounds__(1024, 8) void day_kernel(
    const float* __restrict__ yTrue, const float* __restrict__ yPred,
    float* __restrict__ A, float* __restrict__ P,
    float* __restrict__ SEb, float* __restrict__ SWb, float* __restrict__ Tb,
    int nB)
{
    __shared__ float s_val[1024];
    __shared__ int   s_idx[1024];
    __shared__ int   s_tt[DPS];
    __shared__ float s_red[16];
    __shared__ float s_samp[3][4];

    const int tid  = threadIdx.x;
    const int lane = tid & 63;
    const int wv   = tid >> 6;
    const int b    = blockIdx.x;
    const bool valid = (tid < DPS * 6);        // 1008 active lanes

    const int li  = valid ? tid : 0;
    const int day = li / 6;                    // 0..167
    const int q   = li - day * 6;              // float4 slot within day
    const int h0  = q << 2;                    // first hour of this quad

    const float4* gt = (const float4*)(yTrue + (size_t)b * S_LEN);
    const float4* gp = (const float4*)(yPred + (size_t)b * S_LEN);
    const float4 t = gt[li];
    const float4 p = gp[li];

    // daytime = hour in [6,20]; per-component masks as functions of q
    const bool m0 = (q >= 2);                  // h0+0: 4q   in [6,20] <=> q>=2 (q<=5 always)
    const bool m1 = (q >= 2) && (q <= 4);      // h0+1
    const bool m2 = (q >= 1) && (q <= 4);      // h0+2
    const bool m3 = m2;                        // h0+3

    // ---- true daytime argmax partial ----
    float bv = NEG; int bh = h0;
    { float v;
      v = m0 ? t.x : NEG; if (v > bv) { bv = v; bh = h0;     }
      v = m1 ? t.y : NEG; if (v > bv) { bv = v; bh = h0 + 1; }
      v = m2 ? t.z : NEG; if (v > bv) { bv = v; bh = h0 + 2; }
      v = m3 ? t.w : NEG; if (v > bv) { bv = v; bh = h0 + 3; } }
    s_val[tid] = bv; s_idx[tid] = bh;
    __syncthreads();

    // ---- per-day true peak (threads 0..167) ----
    int tt = 0; float tb = 0.f;
    if (tid < DPS) {
        const int base = tid * 6;
        float v = s_val[base]; int hb = s_idx[base];
#pragma unroll
        for (int j = 1; j < 6; ++j) {
            const float vj = s_val[base + j]; const int hj = s_idx[base + j];
            if (vj > v) { v = vj; hb = hj; }
        }
        tt = hb; tb = v;
        s_tt[tid] = hb;
    }
    __syncthreads();

    // ---- pred argmax partial + weighted squared-error partial ----
    const int ttd = s_tt[day];                 // broadcast read (6 lanes/addr)
    float bpv = NEG; int bph = h0;
    { float v;
      v = m0 ? p.x : NEG; if (v > bpv) { bpv = v; bph = h0;     }
      v = m1 ? p.y : NEG; if (v > bpv) { bpv = v; bph = h0 + 1; }
      v = m2 ? p.z : NEG; if (v > bpv) { bpv = v; bph = h0 + 2; }
      v = m3 ? p.w : NEG; if (v > bpv) { bpv = v; bph = h0 + 3; } }

    const int wlo = ttd - 2, whi = ttd + 2;
    float se = 0.f;
    { float bw, w, d; int h;
      h = h0;     bw = m0 ? 2.f : 0.5f; w = (h >= wlo && h <= whi) ? 3.f * bw : bw; d = p.x - t.x; se = fmaf(w * d, d, se);
      h = h0 + 1; bw = m1 ? 2.f : 0.5f; w = (h >= wlo && h <= whi) ? 3.f * bw : bw; d = p.y - t.y; se = fmaf(w * d, d, se);
      h = h0 + 2; bw = m2 ? 2.f : 0.5f; w = (h >= wlo && h <= whi) ? 3.f * bw : bw; d = p.z - t.z; se = fmaf(w * d, d, se);
      h = h0 + 3; bw = m3 ? 2.f : 0.5f; w = (h >= wlo && h <= whi) ? 3.f * bw : bw; d = p.w - t.w; se = fmaf(w * d, d, se); }
    if (!valid) se = 0.f;
    s_val[tid] = bpv; s_idx[tid] = bph;        // safe: phase-3 readers done (post-barrier)

    // block-level se reduce (all 16 waves)
#pragma unroll
    for (int o = 32; o > 0; o >>= 1) se += __shfl_down(se, o, 64);
    if (lane == 0) s_red[wv] = se;
    __syncthreads();

    // ---- per-day finalize + per-sample reduce (waves 0..2, wave-aligned) ----
    if (tid < 192) {
        float tbv = 0.f, dpk2 = 0.f, sw = 0.f, te = 0.f;
        if (tid < DPS) {
            const int base = tid * 6;
            float v = s_val[base]; int hb = s_idx[base];
#pragma unroll
            for (int j = 1; j < 6; ++j) {
                const float vj = s_val[base + j]; const int hj = s_idx[base + j];
                if (vj > v) { v = vj; hb = hj; }
            }
            // sum of step weights per day, closed form (exact in f32):
            // 34.5 base + 2x(base over [tt-2,tt+2]); night hours in window:
            const int n = max(0, 8 - tt) + max(0, tt - 18);
            sw = 54.5f - 3.f * (float)n;
            te = fabsf((float)(hb - tt));
            const float dpk = v - tb;
            dpk2 = dpk * dpk;
            tbv = tb;
        }
#pragma unroll
        for (int o = 32; o > 0; o >>= 1) {
            tbv  += __shfl_down(tbv,  o, 64);
            dpk2 += __shfl_down(dpk2, o, 64);
            sw   += __shfl_down(sw,   o, 64);
            te   += __shfl_down(te,   o, 64);
        }
        if (lane == 0) {
            s_samp[wv][0] = tbv; s_samp[wv][1] = dpk2;
            s_samp[wv][2] = sw;  s_samp[wv][3] = te;
        }
    }
    __syncthreads();

    if (tid == 0) {
        const float sA = s_samp[0][0] + s_samp[1][0] + s_samp[2][0];
        const float sP = s_samp[0][1] + s_samp[1][1] + s_samp[2][1];
        const float sW = s_samp[0][2] + s_samp[1][2] + s_samp[2][2];
        const float sT = s_samp[0][3] + s_samp[1][3] + s_samp[2][3];
        float e = 0.f;
#pragma unroll
        for (int k = 0; k < 16; ++k) e += s_red[k];
        A[b]   = sA * (1.0f / (float)DPS);
        P[b]   = sP;
        SEb[b] = e;
        SWb[b] = sW;
        Tb[b]  = sT;
    }
}

// ========== kernel B: parallel rank-by-counting quantile (unchanged) ==========

__global__ __launch_bounds__(256) void rank_kernel(
    const float* __restrict__ A, float* __restrict__ qout, int nB)
{
    __shared__ float sA[NB_MAX];
    const int tid = threadIdx.x;

    for (int i = tid; i < nB; i += 256) sA[i] = A[i];
    __syncthreads();

    const int b = blockIdx.x * 64 + (tid >> 2);
    const int quar = tid & 3;
    if (b >= nB) return;
    const float v = sA[b];
    const int span = nB / 4;
    const float4* s4 = (const float4*)(sA + quar * span);

    int cl = 0, ce = 0;
    for (int i = 0; i < span / 4; ++i) {
        float4 x = s4[i];
        cl += (x.x < v) + (x.y < v) + (x.z < v) + (x.w < v);
        ce += (x.x == v) + (x.y == v) + (x.z == v) + (x.w == v);
    }
    cl += __shfl_xor(cl, 1, 64); ce += __shfl_xor(ce, 1, 64);
    cl += __shfl_xor(cl, 2, 64); ce += __shfl_xor(ce, 2, 64);

    if (quar == 0) {
        double pos = 0.75 * (double)(nB - 1);
        int lo = (int)pos;
        int hi = (lo + 1 < nB) ? lo + 1 : lo;
        if (lo >= cl && lo < cl + ce) qout[0] = v;
        if (hi >= cl && hi < cl + ce) qout[1] = v;
    }
}

// ========== kernel C: final scalar (unchanged) ==========

__device__ inline double block_reduce_d(double v, double* scratch, int tid) {
#pragma unroll
    for (int o = 32; o > 0; o >>= 1) v += __shfl_down(v, o, 64);
    if ((tid & 63) == 0) scratch[tid >> 6] = v;
    __syncthreads();
    double r = 0.0;
    if (tid == 0) r = scratch[0] + scratch[1] + scratch[2] + scratch[3];
    __syncthreads();
    return r;
}

__global__ __launch_bounds__(256) void final_kernel(
    const float* __restrict__ SEb, const float* __restrict__ SWb,
    const float* __restrict__ Tb, const float* __restrict__ P,
    const float* __restrict__ A, const float* __restrict__ qout,
    float* __restrict__ out, int nB, int nBlk)
{
    __shared__ double s_dred[4];
    const int tid = threadIdx.x;

    double pos = 0.75 * (double)(nB - 1);
    double frac = pos - (double)((int)pos);
    float thr = (float)((double)qout[0] + frac * ((double)qout[1] - (double)qout[0]));

    double se = 0.0, sw = 0.0, te = 0.0, wp = 0.0, wsum = 0.0;
    for (int i = tid; i < nBlk; i += 256) {
        se += (double)SEb[i];
        sw += (double)SWb[i];
        te += (double)Tb[i];
    }
    for (int b = tid; b < nB; b += 256) {
        float w = (A[b] > thr) ? 1.5f : 1.0f;
        wp   += (double)w * (double)P[b];
        wsum += (double)w;
    }
    se   = block_reduce_d(se,   s_dred, tid);
    sw   = block_reduce_d(sw,   s_dred, tid);
    te   = block_reduce_d(te,   s_dred, tid);
    wp   = block_reduce_d(wp,   s_dred, tid);
    wsum = block_reduce_d(wsum, s_dred, tid);

    if (tid == 0) {
        double L_overall = se / sw;
        double L_peak    = wp / ((double)DPS * wsum);
        double L_timing  = 10.0 * te / ((double)nB * (double)DPS);
        out[0] = (float)(L_overall + 2.0 * L_peak + L_timing);
    }
}

// ========== launcher ==========

extern "C" void kernel_launch(void* const* d_in, const int* in_sizes, int n_in,
                              void* d_out, int out_size, void* d_ws, size_t ws_size,
                              hipStream_t stream) {
    const float* y_pred = (const float*)d_in[0];
    const float* y_true = (const float*)d_in[1];
    int total = in_sizes[0];
    int nB = total / S_LEN;                       // 4096

    float* ws  = (float*)d_ws;
    float* A   = ws;
    float* P   = A   + (size_t)nB;
    float* SEb = P   + (size_t)nB;
    float* SWb = SEb + (size_t)nB;
    float* Tb  = SWb + (size_t)nB;
    float* q   = Tb  + (size_t)nB;

    day_kernel<<<nB, 1024, 0, stream>>>(y_true, y_pred, A, P, SEb, SWb, Tb, nB);
    rank_kernel<<<(nB + 63) / 64, 256, 0, stream>>>(A, q, nB);
    final_kernel<<<1, 256, 0, stream>>>(SEb, SWb, Tb, P, A, q, (float*)d_out, nB, nB);
}